// Round 9
// baseline (134.267 us; speedup 1.0000x reference)
//
#include <hip/hip_runtime.h>
#include <math.h>

typedef _Float16 half_t;
typedef _Float16 half8 __attribute__((ext_vector_type(8)));
typedef _Float16 half4 __attribute__((ext_vector_type(4)));
typedef _Float16 half2v __attribute__((ext_vector_type(2)));
typedef float f32x4 __attribute__((ext_vector_type(4)));
typedef float f32x16 __attribute__((ext_vector_type(16)));
typedef unsigned int uint4v __attribute__((ext_vector_type(4)));

#define MFMA_S(a, b, c) __builtin_amdgcn_mfma_f32_32x32x16_f16((a), (b), (c), 0, 0, 0)

static constexpr int kM  = 512;
static constexpr int kD  = 64;
static constexpr int kKL = 2560;
static constexpr int kL  = 2048;
// ws (halves): q_scaled | K [bh][k][d] | Vc chunked [bh][80][64][32] | peT [l][d]
static constexpr int WS_QS  = 0;                    // 1,048,576
static constexpr int WS_KB  = 1048576;              // 5,242,880
static constexpr int WS_VC  = WS_KB + 5242880;      // 5,242,880
static constexpr int WS_PET = WS_VC + 5242880;      // 131,072
// byte offsets past the half region (11,665,408 halves = 23,330,816 B):
static constexpr size_t WS_ZP_B = 23330816;         // zp f32 [4][16384]   (256 KB)
static constexpr size_t WS_PO_B = WS_ZP_B + 262144; // po f32 [4][16384][64] (16 MB)

// ---------- K1a: q/k convert (split from prep for per-dispatch profiling) ----------
__global__ __launch_bounds__(256) void prep_cvt(const float* __restrict__ q,
    const float* __restrict__ k, half_t* __restrict__ ws) {
  const int i = blockIdx.x * 256 + threadIdx.x;
  const float QS = 0.125f * 1.4426950408889634f;  // 1/sqrt(64) * log2(e)
  const float* src; half_t* dst; float sc;
  if (i < 131072) { src = q + (size_t)i * 8; dst = ws + WS_QS + (size_t)i * 8; sc = QS; }
  else { const int j = i - 131072; src = k + (size_t)j * 8; dst = ws + WS_KB + (size_t)j * 8; sc = 1.0f; }
  const float4 a = ((const float4*)src)[0];
  const float4 bb = ((const float4*)src)[1];
  half_t tt[8];
  tt[0] = (half_t)(a.x * sc);  tt[1] = (half_t)(a.y * sc);
  tt[2] = (half_t)(a.z * sc);  tt[3] = (half_t)(a.w * sc);
  tt[4] = (half_t)(bb.x * sc); tt[5] = (half_t)(bb.y * sc);
  tt[6] = (half_t)(bb.z * sc); tt[7] = (half_t)(bb.w * sc);
  *(int4*)dst = *(int4*)tt;
}

// ---------- K1b: V chunked-transpose + pe transpose ----------
__global__ __launch_bounds__(256) void prep_tr(const float* __restrict__ v,
    const float* __restrict__ pe, half_t* __restrict__ ws) {
  __shared__ float ls[64 * 72];
  const int b = blockIdx.x, t = threadIdx.x;   // grid 1312: 1280 V + 32 pe
  const bool isV = (b < 1280);
  int bh = 0, kt = 0, b3 = 0;
  const float* src; int sstride;
  if (isV) {
    bh = b / 40; kt = b % 40;
    src = v + (size_t)(bh * 2560 + kt * 64) * 64; sstride = 64;
  } else {
    b3 = b - 1280;
    src = pe + (size_t)b3 * 64; sstride = 2048;
  }
  const int rr = t >> 4, cq = (t & 15) * 4;
#pragma unroll
  for (int p = 0; p < 4; ++p) {
    const float4 x = *(const float4*)(src + (size_t)(p * 16 + rr) * sstride + cq);
    *(float4*)(ls + (p * 16 + rr) * 72 + cq) = x;
  }
  __syncthreads();
  const int oc = t >> 2, ch = t & 3;
  half_t tmp[16];
#pragma unroll
  for (int i2 = 0; i2 < 16; ++i2) tmp[i2] = (half_t)ls[(ch * 16 + i2) * 72 + oc];
  half_t* o;
  if (isV) {
    o = ws + WS_VC + (size_t)bh * 163840 + ((kt << 1) + (ch >> 1)) * 2048 + oc * 32 + ((ch & 1) << 4);
  } else {
    o = ws + WS_PET + ((size_t)b3 * 64 + oc) * 64 + ch * 16;
  }
  ((int4*)o)[0] = ((int4*)tmp)[0];
  ((int4*)o)[1] = ((int4*)tmp)[1];
}

// ---------- K2: 32x32-MFMA split-K attention ----------
// grid 512 = 32bh x 4 m-blocks(128 rows) x 4 K-splits (17 chunks each);
// block 256 (4 waves); wave w: 32-row x 32-key tile per step via
// v_mfma_f32_32x32x16_f16: S^T = K.Q^T (4), PE bias (4), PV O^T = V^T.P (4).
// Best measured: 41.4us (R8: R16 base + hoisted pet gather). This round is a
// pure DIAGNOSIS split of prep (no attn change): the 256MiB harness re-poison
// fill (41.6us, 80% HBM peak) surfaced in top-5, implying prep+norm+gaps
// ~51us with prep never visible. prep is now two named dispatches.
// Layouts (32x32x16): A[m=lane&31][k=8*(lane>>5)+j]; B[k=8*(lane>>5)+j][n=lane&31];
// C: col=lane&31, row=(reg&3)+8*(reg>>2)+4*(lane>>5).
// Em strip (ring 64, u=(l+m)&63): scalar b16 writes (wrap-safe), b64 reads
// (no-wrap: read base = B+8q+4h is a multiple of 4).
// LDS: K 2x4608 | Vc 2x5120 | Em 4x4352 = 36,864 B.
__global__ __launch_bounds__(256, 2) void attn_kernel(
    const half_t* __restrict__ ws, const float* __restrict__ cvp,
    float* __restrict__ po, float* __restrict__ zp) {

  __shared__ __align__(16) char smem[36864];
  half_t* lsh = (half_t*)smem;

  const int tid  = threadIdx.x;
  const int lane = tid & 63;
  const int w    = tid >> 6;                    // wave 0..3
  const int c32  = lane & 31;                   // MFMA col (query m / key / d)
  const int h    = lane >> 5;                   // half-wave

  const int id = blockIdx.x;                    // 512
  const int bh = ((id & 7) << 2) | (id >> 7);   // XCD-aware
  const int mid = (id >> 3) & 15;
  const int mb = mid & 3, sp = mid >> 2;
  const int m0 = mb << 7;                       // 128 rows per block
  const int g0 = sp * 17;                       // chunks [g0, g0+17)

  const float cvl = cvp[bh & 7] * 2048.0f - 2047.0f;  // mask = clamp((l+cvl)/64+1,0,1)
  const float cvO = cvl * 0.015625f + 1.0f;

  const half_t* kb  = ws + WS_KB + (size_t)bh * (kKL * kD);
  const half_t* vcb = ws + WS_VC + (size_t)bh * (kKL * kD);
  const half_t* pet = ws + WS_PET;

  // Q B-frags: B[k=d=16t+8h+j][n=m=c32], t=0..3
  const half_t* qrow = ws + WS_QS + (size_t)(bh * kM + m0 + 32 * w + c32) * kD;
  half8 bq[4];
#pragma unroll
  for (int t = 0; t < 4; ++t) bq[t] = *(const half8*)(qrow + t * 16 + h * 8);

  // LDS (halves): K ring 2x2304 @0 | Vc ring 2x2560 @4608 | Em 4x2176 @9728
  half_t* stf = lsh + 9728 + w * 2176 + c32 * 68;     // Em strip row m=c32

  int4 stgK, stgV;
  auto issueKV = [&](int gg) {
    const int r = tid >> 3, seg = tid & 7;
    const int krow = m0 + (gg << 5) + r;               // max 2559
    stgK = *(const int4*)(kb + (size_t)krow * kD + seg * 8);
    const int vch = (m0 >> 5) + gg;                    // max 79
    stgV = *(const int4*)(vcb + (size_t)vch * 2048 + tid * 8);
  };
  auto commitKV = [&](int gg) {
    const int sK = (gg & 1) * 2304;
    const int sV = 4608 + (gg & 1) * 2560;
    const int r = tid >> 3, seg = tid & 7;
    *(int4*)(lsh + sK + r * 72 + seg * 8) = stgK;
    const int d = tid >> 2, ks = (tid & 3) * 8;
    *(int4*)(lsh + sV + d * 40 + ks) = stgV;
  };

  // pet gather for PE window [wb, wb+32) (divergent rows, clamped)
  auto petLoad = [&](int wb, half8* p) {
    int l = wb + c32; l = l < 0 ? 0 : (l > kL - 1 ? kL - 1 : l);
    const half_t* pp = pet + (size_t)l * kD;
#pragma unroll
    for (int t = 0; t < 4; ++t) p[t] = *(const half8*)(pp + t * 16 + h * 8);
  };
  auto peMFMA = [&](const half8* p) -> f32x16 {
    f32x16 a = {};
#pragma unroll
    for (int t = 0; t < 4; ++t) a = MFMA_S(p[t], bq[t], a);
    return a;
  };
  // Store bias' = pe_bias + log2(mask) (f16, log2 domain; -inf == masked out).
  auto stripWrite = [&](int wb, const f32x16& a) {
    const int allone  = (wb >= 0) && (wb + 31 <= kL - 1) && (wb + cvl >= 0.0f);
    const int allzero = (wb > kL - 1) || (wb + 31 < 0) || ((float)(wb + 31) + cvl <= -64.0f);
#pragma unroll
    for (int reg = 0; reg < 16; ++reg) {
      const int lr = (reg & 3) + 8 * (reg >> 2) + 4 * h;
      const int l  = wb + lr;
      float bl;
      if (allzero) bl = -HUGE_VALF;
      else if (allone) bl = a[reg];
      else {
        const float mk = fminf(fmaxf((float)l * 0.015625f + cvO, 0.0f), 1.0f);
        const float lg = __builtin_amdgcn_logf(mk);   // v_log_f32: log2; log2(0) = -inf
        bl = ((unsigned)l < (unsigned)kL) ? a[reg] + lg : -HUGE_VALF;
      }
      stf[(l + c32) & 63] = (half_t)bl;
    }
  };

  // ---- prime: K/V chunk g0 + Em windows [B0-32, B0) and [B0, B0+32) ----
  issueKV(g0);
  const int B0 = (g0 << 5) - 32 * w;
  {
    half8 pq[4];
    petLoad(B0 - 32, pq); stripWrite(B0 - 32, peMFMA(pq));
    petLoad(B0,      pq); stripWrite(B0,      peMFMA(pq));
  }
  commitKV(g0);
  __syncthreads();

  float zmc = 0.0f;
  f32x16 o0 = {}, o1 = {};                      // O^T d in [0,32) / [32,64)

  half8 pp[4];
  for (int t = 0; t < 17; ++t) {
    const int g = g0 + t;
    const bool more = (t < 16);
    const int B = (g << 5) - 32 * w;            // l of key0 vs m=c32=0
    if (more) {
      issueKV(g + 1);
      petLoad(B + 32, pp);                      // hoisted: latency hides under step
    }

    const int sK = (g & 1) * 2304;
    const int sV = 4608 + (g & 1) * 2560;

    // K A-frags: A[m=key=c32][k=16t+8h+j]
    half8 ak[4];
#pragma unroll
    for (int kt = 0; kt < 4; ++kt)
      ak[kt] = *(const half8*)(lsh + sK + c32 * 72 + kt * 16 + h * 8);

    // bias' quads (written at previous step): u = B + 8q + 4h (+r), mult of 4 -> no wrap
    half4 emq[4];
#pragma unroll
    for (int q = 0; q < 4; ++q)
      emq[q] = *(const half4*)(stf + ((B + 8 * q + 4 * h) & 63));

    // V^T A-frags: A[m=d-32dh=c32][k=16kt+8h+j]
    half8 av[2][2];
#pragma unroll
    for (int dh = 0; dh < 2; ++dh)
#pragma unroll
      for (int kt = 0; kt < 2; ++kt)
        av[dh][kt] = *(const half8*)(lsh + sV + (32 * dh + c32) * 40 + kt * 16 + h * 8);

    // ---- S^T = K.Q^T ----
    f32x16 s = {};
#pragma unroll
    for (int kt = 0; kt < 4; ++kt) s = MFMA_S(ak[kt], bq[kt], s);

    // ---- softmax: pm = exp2(s + bias'), f16 RNE convert ----
    float pm[16];
#pragma unroll
    for (int reg = 0; reg < 16; ++reg) {
      pm[reg] = __builtin_amdgcn_exp2f(s[reg] + (float)emq[reg >> 2][reg & 3]);
      zmc += pm[reg];
    }
    // pack pairs: W[q] covers keys {2q,2q+1} of this half's C-key-set
    unsigned Wp[8];
#pragma unroll
    for (int q = 0; q < 8; ++q) {
      const half2v hp = { (half_t)pm[2 * q], (half_t)pm[2 * q + 1] };
      Wp[q] = __builtin_bit_cast(unsigned, hp);
    }
    // C->B refragmentation in-register: half-wave exchange.
    const auto r0 = __builtin_amdgcn_permlane32_swap(Wp[0], Wp[2], false, false);
    const auto r1 = __builtin_amdgcn_permlane32_swap(Wp[1], Wp[3], false, false);
    const auto r2 = __builtin_amdgcn_permlane32_swap(Wp[4], Wp[6], false, false);
    const auto r3 = __builtin_amdgcn_permlane32_swap(Wp[5], Wp[7], false, false);
    const uint4v u0 = { (unsigned)r0[0], (unsigned)r1[0], (unsigned)r0[1], (unsigned)r1[1] };
    const uint4v u1 = { (unsigned)r2[0], (unsigned)r3[0], (unsigned)r2[1], (unsigned)r3[1] };
    const half8 pb0 = __builtin_bit_cast(half8, u0);   // B[k=8h+j][m], keys 0..15
    const half8 pb1 = __builtin_bit_cast(half8, u1);   // keys 16..31

    // ---- PV: O^T[d][m] += V^T.P ----
    o0 = MFMA_S(av[0][0], pb0, o0);
    o0 = MFMA_S(av[0][1], pb1, o0);
    o1 = MFMA_S(av[1][0], pb0, o1);
    o1 = MFMA_S(av[1][1], pb1, o1);

    // ---- bias window for t+1 (after reads): [B+32, B+64) ----
    if (more) {
      stripWrite(B + 32, peMFMA(pp));
      commitKV(g + 1);
    }
    __syncthreads();
  }

  // ---- epilogue: plain partial stores (no atomics) ----
  // loop-end barrier already fenced all waves' LDS reads; overlay is safe.
  float* Ow = (float*)smem + (size_t)w * 2176;  // [32 m][stride 68] f32, wave-local
#pragma unroll
  for (int q = 0; q < 4; ++q) {
    *(f32x4*)(Ow + c32 * 68 + 0  + 8 * q + 4 * h) =
        f32x4{o0[q * 4], o0[q * 4 + 1], o0[q * 4 + 2], o0[q * 4 + 3]};
    *(f32x4*)(Ow + c32 * 68 + 32 + 8 * q + 4 * h) =
        f32x4{o1[q * 4], o1[q * 4 + 1], o1[q * 4 + 2], o1[q * 4 + 3]};
  }
  zmc += __shfl_xor(zmc, 32);
  const int rowbase = bh * kM + m0 + 32 * w;
  if (lane < 32) zp[(size_t)sp * 16384 + rowbase + c32] = zmc;
  float* pob = po + ((size_t)sp * 16384 + rowbase) * 64;
#pragma unroll
  for (int u = 0; u < 8; ++u) {
    const int row = u * 4 + (lane >> 4);        // wave-local row 0..31
    const int d4 = (lane & 15) << 2;
    *(f32x4*)(pob + (size_t)row * 64 + d4) = *(const f32x4*)(Ow + row * 68 + d4);
  }
}

// ---------- K3: 4-way split reduce + normalize ----------
__global__ __launch_bounds__(256) void norm_kernel(const float* __restrict__ zp,
    const float* __restrict__ po, float* __restrict__ out) {
  const int i = blockIdx.x * 256 + threadIdx.x;   // 262,144
  const int row = i >> 4, d4 = (i & 15) << 2;
  const float z = zp[row] + zp[16384 + row] + zp[32768 + row] + zp[49152 + row];
  const float inv = 1.0f / (z + 1e-20f);
  f32x4 a = *(const f32x4*)(po + (size_t)row * 64 + d4);
  const f32x4 b = *(const f32x4*)(po + 1048576u + (size_t)row * 64 + d4);
  const f32x4 c = *(const f32x4*)(po + 2097152u + (size_t)row * 64 + d4);
  const f32x4 d = *(const f32x4*)(po + 3145728u + (size_t)row * 64 + d4);
  a = a + b + c + d;
  *(f32x4*)(out + (size_t)row * 64 + d4) = a * inv;
}

extern "C" void kernel_launch(void* const* d_in, const int* in_sizes, int n_in,
                              void* d_out, int out_size, void* d_ws, size_t ws_size,
                              hipStream_t stream) {
  (void)in_sizes; (void)n_in; (void)out_size; (void)ws_size;
  const float* q  = (const float*)d_in[0];
  const float* k  = (const float*)d_in[1];
  const float* v  = (const float*)d_in[2];
  const float* pe = (const float*)d_in[3];
  const float* cv = (const float*)d_in[4];
  half_t* ws = (half_t*)d_ws;   // needs ~40.4 MB
  float* out = (float*)d_out;
  float* zp = (float*)((char*)d_ws + WS_ZP_B);
  float* po = (float*)((char*)d_ws + WS_PO_B);

  prep_cvt<<<3072, 256, 0, stream>>>(q, k, ws);
  prep_tr<<<1312, 256, 0, stream>>>(v, pe, ws);
  attn_kernel<<<512, 256, 0, stream>>>(ws, cv, po, zp);
  norm_kernel<<<1024, 256, 0, stream>>>(zp, po, out);
}

// Round 10
// 131.814 us; speedup vs baseline: 1.0186x; 1.0186x over previous
//
#include <hip/hip_runtime.h>
#include <math.h>

typedef _Float16 half_t;
typedef _Float16 half8 __attribute__((ext_vector_type(8)));
typedef _Float16 half4 __attribute__((ext_vector_type(4)));
typedef _Float16 half2v __attribute__((ext_vector_type(2)));
typedef float f32x4 __attribute__((ext_vector_type(4)));
typedef float f32x16 __attribute__((ext_vector_type(16)));
typedef unsigned int uint4v __attribute__((ext_vector_type(4)));

#define MFMA_S(a, b, c) __builtin_amdgcn_mfma_f32_32x32x16_f16((a), (b), (c), 0, 0, 0)

static constexpr int kM  = 512;
static constexpr int kD  = 64;
static constexpr int kKL = 2560;
static constexpr int kL  = 2048;
// ws (halves): Vc chunked [bh][80][64][32] | peT [l][d]   (q/k now read as f32 by attn)
static constexpr int WS_VC  = 0;                    // 5,242,880
static constexpr int WS_PET = WS_VC + 5242880;      // 131,072
// byte offsets past the half region (5,373,952 halves = 10,747,904 B):
static constexpr size_t WS_ZP_B = 10747904;         // zp f32 [4][16384]   (256 KB)
static constexpr size_t WS_PO_B = WS_ZP_B + 262144; // po f32 [4][16384][64] (16 MB)

// ---------- K1: V chunked-transpose + pe transpose ----------
// (q/k conversion ELIMINATED: attn reads q/k f32 directly and converts in
// staging, which is latency-hidden. This halves prep's traffic and removes a
// dispatch; if the unexplained ~40us prep-region cost was its work, total
// drops accordingly — ablation that is also the fix.)
__global__ __launch_bounds__(256) void prep_tr(const float* __restrict__ v,
    const float* __restrict__ pe, half_t* __restrict__ ws) {
  __shared__ float ls[64 * 72];
  const int b = blockIdx.x, t = threadIdx.x;   // grid 1312: 1280 V + 32 pe
  const bool isV = (b < 1280);
  int bh = 0, kt = 0, b3 = 0;
  const float* src; int sstride;
  if (isV) {
    bh = b / 40; kt = b % 40;
    src = v + (size_t)(bh * 2560 + kt * 64) * 64; sstride = 64;
  } else {
    b3 = b - 1280;
    src = pe + (size_t)b3 * 64; sstride = 2048;
  }
  const int rr = t >> 4, cq = (t & 15) * 4;
#pragma unroll
  for (int p = 0; p < 4; ++p) {
    const float4 x = *(const float4*)(src + (size_t)(p * 16 + rr) * sstride + cq);
    *(float4*)(ls + (p * 16 + rr) * 72 + cq) = x;
  }
  __syncthreads();
  const int oc = t >> 2, ch = t & 3;
  half_t tmp[16];
#pragma unroll
  for (int i2 = 0; i2 < 16; ++i2) tmp[i2] = (half_t)ls[(ch * 16 + i2) * 72 + oc];
  half_t* o;
  if (isV) {
    o = ws + WS_VC + (size_t)bh * 163840 + ((kt << 1) + (ch >> 1)) * 2048 + oc * 32 + ((ch & 1) << 4);
  } else {
    o = ws + WS_PET + ((size_t)b3 * 64 + oc) * 64 + ch * 16;
  }
  ((int4*)o)[0] = ((int4*)tmp)[0];
  ((int4*)o)[1] = ((int4*)tmp)[1];
}

// ---------- K2: 32x32-MFMA split-K attention ----------
// grid 512 = 32bh x 4 m-blocks(128 rows) x 4 K-splits (17 chunks each);
// block 256 (4 waves); wave w: 32-row x 32-key tile per step via
// v_mfma_f32_32x32x16_f16: S^T = K.Q^T (4), PE bias (4), PV O^T = V^T.P (4).
// R21 vs R19 (best, attn 41.4us): K staged from f32 input (2 float4 loads,
// convert in commitKV — same RNE as the deleted prep_cvt, bit-identical);
// Q loaded f32 + scaled by QS in prologue. Staging is latency-hidden
// (attn at 9% HBM), so this absorbs prep_cvt's 36MB of traffic for free.
// Layouts (32x32x16): A[m=lane&31][k=8*(lane>>5)+j]; B[k=8*(lane>>5)+j][n=lane&31];
// C: col=lane&31, row=(reg&3)+8*(reg>>2)+4*(lane>>5).
// Em strip (ring 64, u=(l+m)&63): scalar b16 writes (wrap-safe), b64 reads
// (no-wrap: read base = B+8q+4h is a multiple of 4).
// LDS: K 2x4608 | Vc 2x5120 | Em 4x4352 = 36,864 B.
__global__ __launch_bounds__(256, 2) void attn_kernel(
    const float* __restrict__ qg, const float* __restrict__ kg,
    const half_t* __restrict__ ws, const float* __restrict__ cvp,
    float* __restrict__ po, float* __restrict__ zp) {

  __shared__ __align__(16) char smem[36864];
  half_t* lsh = (half_t*)smem;

  const int tid  = threadIdx.x;
  const int lane = tid & 63;
  const int w    = tid >> 6;                    // wave 0..3
  const int c32  = lane & 31;                   // MFMA col (query m / key / d)
  const int h    = lane >> 5;                   // half-wave

  const int id = blockIdx.x;                    // 512
  const int bh = ((id & 7) << 2) | (id >> 7);   // XCD-aware
  const int mid = (id >> 3) & 15;
  const int mb = mid & 3, sp = mid >> 2;
  const int m0 = mb << 7;                       // 128 rows per block
  const int g0 = sp * 17;                       // chunks [g0, g0+17)

  const float cvl = cvp[bh & 7] * 2048.0f - 2047.0f;  // mask = clamp((l+cvl)/64+1,0,1)
  const float cvO = cvl * 0.015625f + 1.0f;

  const float*  kbF = kg + (size_t)bh * (kKL * kD);
  const half_t* vcb = ws + WS_VC + (size_t)bh * (kKL * kD);
  const half_t* pet = ws + WS_PET;

  // Q B-frags from f32, scaled: B[k=d=16t+8h+j][n=m=c32], t=0..3
  const float QS = 0.125f * 1.4426950408889634f;      // 1/sqrt(64) * log2(e)
  const float* qrowF = qg + (size_t)(bh * kM + m0 + 32 * w + c32) * kD;
  half8 bq[4];
#pragma unroll
  for (int t = 0; t < 4; ++t) {
    const float4 qa = *(const float4*)(qrowF + t * 16 + h * 8);
    const float4 qb = *(const float4*)(qrowF + t * 16 + h * 8 + 4);
    bq[t] = half8{ (half_t)(qa.x * QS), (half_t)(qa.y * QS),
                   (half_t)(qa.z * QS), (half_t)(qa.w * QS),
                   (half_t)(qb.x * QS), (half_t)(qb.y * QS),
                   (half_t)(qb.z * QS), (half_t)(qb.w * QS) };
  }

  // LDS (halves): K ring 2x2304 @0 | Vc ring 2x2560 @4608 | Em 4x2176 @9728
  half_t* stf = lsh + 9728 + w * 2176 + c32 * 68;     // Em strip row m=c32

  float4 stgKa, stgKb; int4 stgV;
  auto issueKV = [&](int gg) {
    const int r = tid >> 3, seg = tid & 7;
    const int krow = m0 + (gg << 5) + r;               // max 2559
    const float* kp = kbF + (size_t)krow * kD + seg * 8;
    stgKa = *(const float4*)kp;
    stgKb = *(const float4*)(kp + 4);
    const int vch = (m0 >> 5) + gg;                    // max 79
    stgV = *(const int4*)(vcb + (size_t)vch * 2048 + tid * 8);
  };
  auto commitKV = [&](int gg) {
    const int sK = (gg & 1) * 2304;
    const int sV = 4608 + (gg & 1) * 2560;
    const int r = tid >> 3, seg = tid & 7;
    half_t tk[8];
    tk[0] = (half_t)stgKa.x; tk[1] = (half_t)stgKa.y;
    tk[2] = (half_t)stgKa.z; tk[3] = (half_t)stgKa.w;
    tk[4] = (half_t)stgKb.x; tk[5] = (half_t)stgKb.y;
    tk[6] = (half_t)stgKb.z; tk[7] = (half_t)stgKb.w;
    *(int4*)(lsh + sK + r * 72 + seg * 8) = *(int4*)tk;
    const int d = tid >> 2, ks = (tid & 3) * 8;
    *(int4*)(lsh + sV + d * 40 + ks) = stgV;
  };

  // pet gather for PE window [wb, wb+32) (divergent rows, clamped)
  auto petLoad = [&](int wb, half8* p) {
    int l = wb + c32; l = l < 0 ? 0 : (l > kL - 1 ? kL - 1 : l);
    const half_t* pp = pet + (size_t)l * kD;
#pragma unroll
    for (int t = 0; t < 4; ++t) p[t] = *(const half8*)(pp + t * 16 + h * 8);
  };
  auto peMFMA = [&](const half8* p) -> f32x16 {
    f32x16 a = {};
#pragma unroll
    for (int t = 0; t < 4; ++t) a = MFMA_S(p[t], bq[t], a);
    return a;
  };
  // Store bias' = pe_bias + log2(mask) (f16, log2 domain; -inf == masked out).
  auto stripWrite = [&](int wb, const f32x16& a) {
    const int allone  = (wb >= 0) && (wb + 31 <= kL - 1) && (wb + cvl >= 0.0f);
    const int allzero = (wb > kL - 1) || (wb + 31 < 0) || ((float)(wb + 31) + cvl <= -64.0f);
#pragma unroll
    for (int reg = 0; reg < 16; ++reg) {
      const int lr = (reg & 3) + 8 * (reg >> 2) + 4 * h;
      const int l  = wb + lr;
      float bl;
      if (allzero) bl = -HUGE_VALF;
      else if (allone) bl = a[reg];
      else {
        const float mk = fminf(fmaxf((float)l * 0.015625f + cvO, 0.0f), 1.0f);
        const float lg = __builtin_amdgcn_logf(mk);   // v_log_f32: log2; log2(0) = -inf
        bl = ((unsigned)l < (unsigned)kL) ? a[reg] + lg : -HUGE_VALF;
      }
      stf[(l + c32) & 63] = (half_t)bl;
    }
  };

  // ---- prime: K/V chunk g0 + Em windows [B0-32, B0) and [B0, B0+32) ----
  issueKV(g0);
  const int B0 = (g0 << 5) - 32 * w;
  {
    half8 pq[4];
    petLoad(B0 - 32, pq); stripWrite(B0 - 32, peMFMA(pq));
    petLoad(B0,      pq); stripWrite(B0,      peMFMA(pq));
  }
  commitKV(g0);
  __syncthreads();

  float zmc = 0.0f;
  f32x16 o0 = {}, o1 = {};                      // O^T d in [0,32) / [32,64)

  half8 pp[4];
  for (int t = 0; t < 17; ++t) {
    const int g = g0 + t;
    const bool more = (t < 16);
    const int B = (g << 5) - 32 * w;            // l of key0 vs m=c32=0
    if (more) {
      issueKV(g + 1);
      petLoad(B + 32, pp);                      // hoisted: latency hides under step
    }

    const int sK = (g & 1) * 2304;
    const int sV = 4608 + (g & 1) * 2560;

    // K A-frags: A[m=key=c32][k=16t+8h+j]
    half8 ak[4];
#pragma unroll
    for (int kt = 0; kt < 4; ++kt)
      ak[kt] = *(const half8*)(lsh + sK + c32 * 72 + kt * 16 + h * 8);

    // bias' quads (written at previous step): u = B + 8q + 4h (+r), mult of 4 -> no wrap
    half4 emq[4];
#pragma unroll
    for (int q = 0; q < 4; ++q)
      emq[q] = *(const half4*)(stf + ((B + 8 * q + 4 * h) & 63));

    // V^T A-frags: A[m=d-32dh=c32][k=16kt+8h+j]
    half8 av[2][2];
#pragma unroll
    for (int dh = 0; dh < 2; ++dh)
#pragma unroll
      for (int kt = 0; kt < 2; ++kt)
        av[dh][kt] = *(const half8*)(lsh + sV + (32 * dh + c32) * 40 + kt * 16 + h * 8);

    // ---- S^T = K.Q^T ----
    f32x16 s = {};
#pragma unroll
    for (int kt = 0; kt < 4; ++kt) s = MFMA_S(ak[kt], bq[kt], s);

    // ---- softmax: pm = exp2(s + bias'), f16 RNE convert ----
    float pm[16];
#pragma unroll
    for (int reg = 0; reg < 16; ++reg) {
      pm[reg] = __builtin_amdgcn_exp2f(s[reg] + (float)emq[reg >> 2][reg & 3]);
      zmc += pm[reg];
    }
    // pack pairs: W[q] covers keys {2q,2q+1} of this half's C-key-set
    unsigned Wp[8];
#pragma unroll
    for (int q = 0; q < 8; ++q) {
      const half2v hp = { (half_t)pm[2 * q], (half_t)pm[2 * q + 1] };
      Wp[q] = __builtin_bit_cast(unsigned, hp);
    }
    // C->B refragmentation in-register: half-wave exchange.
    const auto r0 = __builtin_amdgcn_permlane32_swap(Wp[0], Wp[2], false, false);
    const auto r1 = __builtin_amdgcn_permlane32_swap(Wp[1], Wp[3], false, false);
    const auto r2 = __builtin_amdgcn_permlane32_swap(Wp[4], Wp[6], false, false);
    const auto r3 = __builtin_amdgcn_permlane32_swap(Wp[5], Wp[7], false, false);
    const uint4v u0 = { (unsigned)r0[0], (unsigned)r1[0], (unsigned)r0[1], (unsigned)r1[1] };
    const uint4v u1 = { (unsigned)r2[0], (unsigned)r3[0], (unsigned)r2[1], (unsigned)r3[1] };
    const half8 pb0 = __builtin_bit_cast(half8, u0);   // B[k=8h+j][m], keys 0..15
    const half8 pb1 = __builtin_bit_cast(half8, u1);   // keys 16..31

    // ---- PV: O^T[d][m] += V^T.P ----
    o0 = MFMA_S(av[0][0], pb0, o0);
    o0 = MFMA_S(av[0][1], pb1, o0);
    o1 = MFMA_S(av[1][0], pb0, o1);
    o1 = MFMA_S(av[1][1], pb1, o1);

    // ---- bias window for t+1 (after reads): [B+32, B+64) ----
    if (more) {
      stripWrite(B + 32, peMFMA(pp));
      commitKV(g + 1);
    }
    __syncthreads();
  }

  // ---- epilogue: plain partial stores (no atomics) ----
  // loop-end barrier already fenced all waves' LDS reads; overlay is safe.
  float* Ow = (float*)smem + (size_t)w * 2176;  // [32 m][stride 68] f32, wave-local
#pragma unroll
  for (int q = 0; q < 4; ++q) {
    *(f32x4*)(Ow + c32 * 68 + 0  + 8 * q + 4 * h) =
        f32x4{o0[q * 4], o0[q * 4 + 1], o0[q * 4 + 2], o0[q * 4 + 3]};
    *(f32x4*)(Ow + c32 * 68 + 32 + 8 * q + 4 * h) =
        f32x4{o1[q * 4], o1[q * 4 + 1], o1[q * 4 + 2], o1[q * 4 + 3]};
  }
  zmc += __shfl_xor(zmc, 32);
  const int rowbase = bh * kM + m0 + 32 * w;
  if (lane < 32) zp[(size_t)sp * 16384 + rowbase + c32] = zmc;
  float* pob = po + ((size_t)sp * 16384 + rowbase) * 64;
#pragma unroll
  for (int u = 0; u < 8; ++u) {
    const int row = u * 4 + (lane >> 4);        // wave-local row 0..31
    const int d4 = (lane & 15) << 2;
    *(f32x4*)(pob + (size_t)row * 64 + d4) = *(const f32x4*)(Ow + row * 68 + d4);
  }
}

// ---------- K3: 4-way split reduce + normalize ----------
__global__ __launch_bounds__(256) void norm_kernel(const float* __restrict__ zp,
    const float* __restrict__ po, float* __restrict__ out) {
  const int i = blockIdx.x * 256 + threadIdx.x;   // 262,144
  const int row = i >> 4, d4 = (i & 15) << 2;
  const float z = zp[row] + zp[16384 + row] + zp[32768 + row] + zp[49152 + row];
  const float inv = 1.0f / (z + 1e-20f);
  f32x4 a = *(const f32x4*)(po + (size_t)row * 64 + d4);
  const f32x4 b = *(const f32x4*)(po + 1048576u + (size_t)row * 64 + d4);
  const f32x4 c = *(const f32x4*)(po + 2097152u + (size_t)row * 64 + d4);
  const f32x4 d = *(const f32x4*)(po + 3145728u + (size_t)row * 64 + d4);
  a = a + b + c + d;
  *(f32x4*)(out + (size_t)row * 64 + d4) = a * inv;
}

extern "C" void kernel_launch(void* const* d_in, const int* in_sizes, int n_in,
                              void* d_out, int out_size, void* d_ws, size_t ws_size,
                              hipStream_t stream) {
  (void)in_sizes; (void)n_in; (void)out_size; (void)ws_size;
  const float* q  = (const float*)d_in[0];
  const float* k  = (const float*)d_in[1];
  const float* v  = (const float*)d_in[2];
  const float* pe = (const float*)d_in[3];
  const float* cv = (const float*)d_in[4];
  half_t* ws = (half_t*)d_ws;   // needs ~27 MB
  float* out = (float*)d_out;
  float* zp = (float*)((char*)d_ws + WS_ZP_B);
  float* po = (float*)((char*)d_ws + WS_PO_B);

  prep_tr<<<1312, 256, 0, stream>>>(v, pe, ws);
  attn_kernel<<<512, 256, 0, stream>>>(q, k, ws, cv, po, zp);
  norm_kernel<<<1024, 256, 0, stream>>>(zp, po, out);
}

// Round 12
// 130.484 us; speedup vs baseline: 1.0290x; 1.0102x over previous
//
#include <hip/hip_runtime.h>
#include <math.h>

typedef _Float16 half_t;
typedef _Float16 half8 __attribute__((ext_vector_type(8)));
typedef _Float16 half4 __attribute__((ext_vector_type(4)));
typedef _Float16 half2v __attribute__((ext_vector_type(2)));
typedef float f32x2 __attribute__((ext_vector_type(2)));
typedef float f32x4 __attribute__((ext_vector_type(4)));
typedef float f32x16 __attribute__((ext_vector_type(16)));
typedef unsigned int uint4v __attribute__((ext_vector_type(4)));

#define MFMA_S(a, b, c) __builtin_amdgcn_mfma_f32_32x32x16_f16((a), (b), (c), 0, 0, 0)

static constexpr int kM  = 512;
static constexpr int kD  = 64;
static constexpr int kKL = 2560;
static constexpr int kL  = 2048;
// ws (halves): Vc chunked [bh][80][64][32] | peT [l][d]   (q/k read as f32 by attn)
static constexpr int WS_VC  = 0;                    // 5,242,880
static constexpr int WS_PET = WS_VC + 5242880;      // 131,072
// byte offsets past the half region (5,373,952 halves = 10,747,904 B):
static constexpr size_t WS_ZP_B = 10747904;         // zp f32 [4][16384]   (256 KB)
static constexpr size_t WS_PO_B = WS_ZP_B + 262144; // po f32 [4][16384][64] (16 MB)

// ---------- K1: V chunked-transpose + pe transpose ----------
__global__ __launch_bounds__(256) void prep_tr(const float* __restrict__ v,
    const float* __restrict__ pe, half_t* __restrict__ ws) {
  __shared__ float ls[64 * 72];
  const int b = blockIdx.x, t = threadIdx.x;   // grid 1312: 1280 V + 32 pe
  const bool isV = (b < 1280);
  int bh = 0, kt = 0, b3 = 0;
  const float* src; int sstride;
  if (isV) {
    bh = b / 40; kt = b % 40;
    src = v + (size_t)(bh * 2560 + kt * 64) * 64; sstride = 64;
  } else {
    b3 = b - 1280;
    src = pe + (size_t)b3 * 64; sstride = 2048;
  }
  const int rr = t >> 4, cq = (t & 15) * 4;
#pragma unroll
  for (int p = 0; p < 4; ++p) {
    const float4 x = *(const float4*)(src + (size_t)(p * 16 + rr) * sstride + cq);
    *(float4*)(ls + (p * 16 + rr) * 72 + cq) = x;
  }
  __syncthreads();
  const int oc = t >> 2, ch = t & 3;
  half_t tmp[16];
#pragma unroll
  for (int i2 = 0; i2 < 16; ++i2) tmp[i2] = (half_t)ls[(ch * 16 + i2) * 72 + oc];
  half_t* o;
  if (isV) {
    o = ws + WS_VC + (size_t)bh * 163840 + ((kt << 1) + (ch >> 1)) * 2048 + oc * 32 + ((ch & 1) << 4);
  } else {
    o = ws + WS_PET + ((size_t)b3 * 64 + oc) * 64 + ch * 16;
  }
  ((int4*)o)[0] = ((int4*)tmp)[0];
  ((int4*)o)[1] = ((int4*)tmp)[1];
}

// ---------- K2: 32x32-MFMA split-K attention ----------
// grid 512 = 32bh x 4 m-blocks x 4 K-splits (17 chunks). 4 waves/block.
// R25 = R10-best structure (attn 45.7us) + chain-VALU cut (R2's measured
// ~12-16cy/removed-chain-op scaling):
//  (a) Em strip stored as F32 (ring 64, stride 66 f32) and consumed as the
//      S-accumulator C-INIT: kills 16 cvt + 16 add per step and moves the
//      Em read to the chain head (hidden under ak loads). f32 bias is MORE
//      precise than the old f16-rounded bias.
//  (b) P pack via v_cvt_pkrtz (8 ops vs 16 cvt + 8 pack). RTZ on P adds
//      ~1e-3 rel err; absmax headroom is 4.6x.
//  (c) zmc pairwise tree (depth 4) instead of 16-long serial add chain.
// R11's distance-2 Em FAILED (absmax 0.29): reads span TWO windows
// (j = B+kr-qm in [B-31,B+31]) so distance-2 needs 3 live windows > ring 64.
// Distance-1 is the only valid 64-ring schedule; the write->read adjacency
// is already fenced by the per-step barrier (lgkmcnt drain) so it costs ~0.
// Layouts (32x32x16): A[m=lane&31][k=8*(lane>>5)+j]; B[k=8*(lane>>5)+j][n=lane&31];
// C: col=lane&31, row=(reg&3)+8*(reg>>2)+4*(lane>>5).
// Em ring (64, pos=(j+qm)&63): b32 writes bank (3qm+c)&31 -> conflict-free;
// b64 reads base mult-of-4 -> no wrap, 2-way max (free).
// LDS: K 2x4608B @0 | Vc 2x5120B @9216 | Em-f32 4x8448B @19456 = 53,248 B.
__global__ __launch_bounds__(256, 2) void attn_kernel(
    const float* __restrict__ qg, const float* __restrict__ kg,
    const half_t* __restrict__ ws, const float* __restrict__ cvp,
    float* __restrict__ po, float* __restrict__ zp) {

  __shared__ __align__(16) char smem[53248];
  half_t* lsh = (half_t*)smem;

  const int tid  = threadIdx.x;
  const int lane = tid & 63;
  const int w    = tid >> 6;                    // wave 0..3
  const int c32  = lane & 31;                   // MFMA col (query m / key / d)
  const int h    = lane >> 5;                   // half-wave

  const int id = blockIdx.x;                    // 512
  const int bh = ((id & 7) << 2) | (id >> 7);   // XCD-aware
  const int mid = (id >> 3) & 15;
  const int mb = mid & 3, sp = mid >> 2;
  const int m0 = mb << 7;                       // 128 rows per block
  const int g0 = sp * 17;                       // chunks [g0, g0+17)

  const float cvl = cvp[bh & 7] * 2048.0f - 2047.0f;  // mask = clamp((l+cvl)/64+1,0,1)
  const float cvO = cvl * 0.015625f + 1.0f;

  const float*  kbF = kg + (size_t)bh * (kKL * kD);
  const half_t* vcb = ws + WS_VC + (size_t)bh * (kKL * kD);
  const half_t* pet = ws + WS_PET;

  // Q B-frags from f32, scaled: B[k=d=16t+8h+j][n=m=c32], t=0..3
  const float QS = 0.125f * 1.4426950408889634f;      // 1/sqrt(64) * log2(e)
  const float* qrowF = qg + (size_t)(bh * kM + m0 + 32 * w + c32) * kD;
  half8 bq[4];
#pragma unroll
  for (int t = 0; t < 4; ++t) {
    const float4 qa = *(const float4*)(qrowF + t * 16 + h * 8);
    const float4 qb = *(const float4*)(qrowF + t * 16 + h * 8 + 4);
    bq[t] = half8{ (half_t)(qa.x * QS), (half_t)(qa.y * QS),
                   (half_t)(qa.z * QS), (half_t)(qa.w * QS),
                   (half_t)(qb.x * QS), (half_t)(qb.y * QS),
                   (half_t)(qb.z * QS), (half_t)(qb.w * QS) };
  }

  // Em f32 strip: base @byte 19456; wave w region 2112 f32; row qm stride 66
  float* stfF = (float*)(smem + 19456) + w * 2112 + c32 * 66;

  float4 stgKa, stgKb; int4 stgV;
  auto issueKV = [&](int gg) {
    const int r = tid >> 3, seg = tid & 7;
    const int krow = m0 + (gg << 5) + r;               // max 2559
    const float* kp = kbF + (size_t)krow * kD + seg * 8;
    stgKa = *(const float4*)kp;
    stgKb = *(const float4*)(kp + 4);
    const int vch = (m0 >> 5) + gg;                    // max 79
    stgV = *(const int4*)(vcb + (size_t)vch * 2048 + tid * 8);
  };
  auto commitKV = [&](int gg) {
    const int sK = (gg & 1) * 2304;
    const int sV = 4608 + (gg & 1) * 2560;
    const int r = tid >> 3, seg = tid & 7;
    half_t tk[8];
    tk[0] = (half_t)stgKa.x; tk[1] = (half_t)stgKa.y;
    tk[2] = (half_t)stgKa.z; tk[3] = (half_t)stgKa.w;
    tk[4] = (half_t)stgKb.x; tk[5] = (half_t)stgKb.y;
    tk[6] = (half_t)stgKb.z; tk[7] = (half_t)stgKb.w;
    *(int4*)(lsh + sK + r * 72 + seg * 8) = *(int4*)tk;
    const int d = tid >> 2, ks = (tid & 3) * 8;
    *(int4*)(lsh + sV + d * 40 + ks) = stgV;
  };

  // pet gather for PE window [wb, wb+32) (divergent rows, clamped)
  auto petLoad = [&](int wb, half8* p) {
    int l = wb + c32; l = l < 0 ? 0 : (l > kL - 1 ? kL - 1 : l);
    const half_t* pp = pet + (size_t)l * kD;
#pragma unroll
    for (int t = 0; t < 4; ++t) p[t] = *(const half8*)(pp + t * 16 + h * 8);
  };
  auto peMFMA = [&](const half8* p) -> f32x16 {
    f32x16 a = {};
#pragma unroll
    for (int t = 0; t < 4; ++t) a = MFMA_S(p[t], bq[t], a);
    return a;
  };
  // Store bias' = pe_bias + log2(mask) as F32 (-inf == masked out).
  auto stripWrite = [&](int wb, const f32x16& a) {
    const int allone  = (wb >= 0) && (wb + 31 <= kL - 1) && (wb + cvl >= 0.0f);
    const int allzero = (wb > kL - 1) || (wb + 31 < 0) || ((float)(wb + 31) + cvl <= -64.0f);
#pragma unroll
    for (int reg = 0; reg < 16; ++reg) {
      const int lr = (reg & 3) + 8 * (reg >> 2) + 4 * h;
      const int l  = wb + lr;
      float bl;
      if (allzero) bl = -HUGE_VALF;
      else if (allone) bl = a[reg];
      else {
        const float mk = fminf(fmaxf((float)l * 0.015625f + cvO, 0.0f), 1.0f);
        const float lg = __builtin_amdgcn_logf(mk);   // v_log_f32: log2; log2(0) = -inf
        bl = ((unsigned)l < (unsigned)kL) ? a[reg] + lg : -HUGE_VALF;
      }
      stfF[(l + c32) & 63] = bl;
    }
  };

  // ---- prime: K/V chunk g0 + Em windows [B0-32, B0) and [B0, B0+32) ----
  issueKV(g0);
  const int B0 = (g0 << 5) - 32 * w;
  {
    half8 pq[4];
    petLoad(B0 - 32, pq); stripWrite(B0 - 32, peMFMA(pq));
    petLoad(B0,      pq); stripWrite(B0,      peMFMA(pq));
  }
  commitKV(g0);
  __syncthreads();

  float zmc = 0.0f;
  f32x16 o0 = {}, o1 = {};                      // O^T d in [0,32) / [32,64)

  half8 pp[4];
  for (int t = 0; t < 17; ++t) {
    const int g = g0 + t;
    const bool more = (t < 16);
    const int B = (g << 5) - 32 * w;            // l of key0 vs m=c32=0
    if (more) {
      issueKV(g + 1);
      petLoad(B + 32, pp);                      // hoisted: latency hides under step
    }

    const int sK = (g & 1) * 2304;
    const int sV = 4608 + (g & 1) * 2560;

    // ---- S accumulator C-INIT from f32 Em ring (chain head, no VALU) ----
    // s[reg] = bias'(qm, j=B+lr-qm) at ring pos (B+lr)&63; b64 pairs, no wrap
    f32x16 s;
#pragma unroll
    for (int q = 0; q < 4; ++q) {
      const int base = (B + 8 * q + 4 * h) & 63;
      const f32x2 lo = *(const f32x2*)(stfF + base);
      const f32x2 hi = *(const f32x2*)(stfF + base + 2);
      s[4 * q + 0] = lo.x; s[4 * q + 1] = lo.y;
      s[4 * q + 2] = hi.x; s[4 * q + 3] = hi.y;
    }

    // K A-frags: A[m=key=c32][k=16t+8h+j]
    half8 ak[4];
#pragma unroll
    for (int kt = 0; kt < 4; ++kt)
      ak[kt] = *(const half8*)(lsh + sK + c32 * 72 + kt * 16 + h * 8);

    // V^T A-frags: A[m=d-32dh=c32][k=16kt+8h+j]
    half8 av[2][2];
#pragma unroll
    for (int dh = 0; dh < 2; ++dh)
#pragma unroll
      for (int kt = 0; kt < 2; ++kt)
        av[dh][kt] = *(const half8*)(lsh + sV + (32 * dh + c32) * 40 + kt * 16 + h * 8);

    // ---- S^T = K.Q^T + bias' (C-init) ----
#pragma unroll
    for (int kt = 0; kt < 4; ++kt) s = MFMA_S(ak[kt], bq[kt], s);

    // ---- softmax: pm = exp2(s); zmc tree-sum; pack via cvt_pkrtz ----
    float pm[16];
#pragma unroll
    for (int reg = 0; reg < 16; ++reg) pm[reg] = __builtin_amdgcn_exp2f(s[reg]);
    {
      const float t0 = (pm[0] + pm[1]) + (pm[2] + pm[3]);
      const float t1 = (pm[4] + pm[5]) + (pm[6] + pm[7]);
      const float t2 = (pm[8] + pm[9]) + (pm[10] + pm[11]);
      const float t3 = (pm[12] + pm[13]) + (pm[14] + pm[15]);
      zmc += (t0 + t1) + (t2 + t3);
    }
    unsigned Wp[8];
#pragma unroll
    for (int q = 0; q < 8; ++q)
      Wp[q] = __builtin_bit_cast(unsigned,
                __builtin_amdgcn_cvt_pkrtz(pm[2 * q], pm[2 * q + 1]));
    // C->B refragmentation in-register: half-wave exchange.
    const auto r0 = __builtin_amdgcn_permlane32_swap(Wp[0], Wp[2], false, false);
    const auto r1 = __builtin_amdgcn_permlane32_swap(Wp[1], Wp[3], false, false);
    const auto r2 = __builtin_amdgcn_permlane32_swap(Wp[4], Wp[6], false, false);
    const auto r3 = __builtin_amdgcn_permlane32_swap(Wp[5], Wp[7], false, false);
    const uint4v u0 = { (unsigned)r0[0], (unsigned)r1[0], (unsigned)r0[1], (unsigned)r1[1] };
    const uint4v u1 = { (unsigned)r2[0], (unsigned)r3[0], (unsigned)r2[1], (unsigned)r3[1] };
    const half8 pb0 = __builtin_bit_cast(half8, u0);   // B[k=8h+j][m], keys 0..15
    const half8 pb1 = __builtin_bit_cast(half8, u1);   // keys 16..31

    // ---- PV: O^T[d][m] += V^T.P ----
    o0 = MFMA_S(av[0][0], pb0, o0);
    o0 = MFMA_S(av[0][1], pb1, o0);
    o1 = MFMA_S(av[1][0], pb0, o1);
    o1 = MFMA_S(av[1][1], pb1, o1);

    // ---- bias window for t+1 (after reads): [B+32, B+64) ----
    if (more) {
      stripWrite(B + 32, peMFMA(pp));
      commitKV(g + 1);
    }
    __syncthreads();
  }

  // ---- epilogue: plain partial stores (no atomics) ----
  // loop-end barrier already fenced all waves' LDS reads; overlay is safe.
  float* Ow = (float*)smem + (size_t)w * 2176;  // [32 m][stride 68] f32, wave-local
#pragma unroll
  for (int q = 0; q < 4; ++q) {
    *(f32x4*)(Ow + c32 * 68 + 0  + 8 * q + 4 * h) =
        f32x4{o0[q * 4], o0[q * 4 + 1], o0[q * 4 + 2], o0[q * 4 + 3]};
    *(f32x4*)(Ow + c32 * 68 + 32 + 8 * q + 4 * h) =
        f32x4{o1[q * 4], o1[q * 4 + 1], o1[q * 4 + 2], o1[q * 4 + 3]};
  }
  zmc += __shfl_xor(zmc, 32);
  const int rowbase = bh * kM + m0 + 32 * w;
  if (lane < 32) zp[(size_t)sp * 16384 + rowbase + c32] = zmc;
  __syncthreads();
  float* pob = po + ((size_t)sp * 16384 + rowbase) * 64;
#pragma unroll
  for (int u = 0; u < 8; ++u) {
    const int row = u * 4 + (lane >> 4);        // wave-local row 0..31
    const int d4 = (lane & 15) << 2;
    *(f32x4*)(pob + (size_t)row * 64 + d4) = *(const f32x4*)(Ow + row * 68 + d4);
  }
}

// ---------- K3: 4-way split reduce + normalize ----------
__global__ __launch_bounds__(256) void norm_kernel(const float* __restrict__ zp,
    const float* __restrict__ po, float* __restrict__ out) {
  const int i = blockIdx.x * 256 + threadIdx.x;   // 262,144
  const int row = i >> 4, d4 = (i & 15) << 2;
  const float z = zp[row] + zp[16384 + row] + zp[32768 + row] + zp[49152 + row];
  const float inv = 1.0f / (z + 1e-20f);
  f32x4 a = *(const f32x4*)(po + (size_t)row * 64 + d4);
  const f32x4 b = *(const f32x4*)(po + 1048576u + (size_t)row * 64 + d4);
  const f32x4 c = *(const f32x4*)(po + 2097152u + (size_t)row * 64 + d4);
  const f32x4 d = *(const f32x4*)(po + 3145728u + (size_t)row * 64 + d4);
  a = a + b + c + d;
  *(f32x4*)(out + (size_t)row * 64 + d4) = a * inv;
}

extern "C" void kernel_launch(void* const* d_in, const int* in_sizes, int n_in,
                              void* d_out, int out_size, void* d_ws, size_t ws_size,
                              hipStream_t stream) {
  (void)in_sizes; (void)n_in; (void)out_size; (void)ws_size;
  const float* q  = (const float*)d_in[0];
  const float* k  = (const float*)d_in[1];
  const float* v  = (const float*)d_in[2];
  const float* pe = (const float*)d_in[3];
  const float* cv = (const float*)d_in[4];
  half_t* ws = (half_t*)d_ws;   // needs ~27 MB
  float* out = (float*)d_out;
  float* zp = (float*)((char*)d_ws + WS_ZP_B);
  float* po = (float*)((char*)d_ws + WS_PO_B);

  prep_tr<<<1312, 256, 0, stream>>>(v, pe, ws);
  attn_kernel<<<512, 256, 0, stream>>>(q, k, ws, cv, po, zp);
  norm_kernel<<<1024, 256, 0, stream>>>(zp, po, out);
}